// Round 1
// baseline (368.552 us; speedup 1.0000x reference)
//
#include <hip/hip_runtime.h>
#include <hip/hip_bf16.h>

// MultiHeadDotProductAttention: b=4, L=2048, E=1024, H=16, D=64
// Pipeline: wtrans (f32->bf16, W^T) -> GEMM q,k,vT -> flash attn -> GEMM out.

typedef __attribute__((ext_vector_type(8))) short bf16x8;
typedef __attribute__((ext_vector_type(4))) float f32x4;

#define MFMA16(a, b, c) __builtin_amdgcn_mfma_f32_16x16x32_bf16((a), (b), (c), 0, 0, 0)

__device__ __forceinline__ short f2bf(float f) {
  union { float f; unsigned u; } v; v.f = f;
  unsigned r = v.u + 0x7fffu + ((v.u >> 16) & 1u);  // RNE
  return (short)(r >> 16);
}

// ---------------------------------------------------------------------------
// Weight transpose + convert: W[k][n] f32 (1024x1024) -> WT[n][k] bf16.
// z in [0,4) selects Wq, Wk, Wv, Wo.
// ---------------------------------------------------------------------------
__global__ __launch_bounds__(256) void wtrans_kernel(
    const float* __restrict__ w0, const float* __restrict__ w1,
    const float* __restrict__ w2, const float* __restrict__ w3,
    short* __restrict__ out) {
  __shared__ float t[32][33];
  const int z = blockIdx.z;
  const float* src = (z == 0) ? w0 : (z == 1) ? w1 : (z == 2) ? w2 : w3;
  short* dst = out + (size_t)z * (1024 * 1024);
  const int x = threadIdx.x & 31, y = threadIdx.x >> 5;
  const int n0 = blockIdx.x * 32, k0 = blockIdx.y * 32;
#pragma unroll
  for (int yy = y; yy < 32; yy += 8)
    t[yy][x] = src[(size_t)(k0 + yy) * 1024 + n0 + x];
  __syncthreads();
#pragma unroll
  for (int yy = y; yy < 32; yy += 8)
    dst[(size_t)(n0 + yy) * 1024 + k0 + x] = f2bf(t[x][yy]);
}

// ---------------------------------------------------------------------------
// GEMM: C[M][N] = A[M][K] * B[N][K]^T   (both operands k-major, "B^T input")
// A rows = output rows, B rows = output cols. 128x128 tile, BK=64,
// 4 waves in 2x2 of 64x64, 16x16x32 bf16 MFMA.
// AF32/BF32: operand is f32 and converted during staging.
// OUTF32: write f32 (else bf16). scale applied in epilogue.
// ---------------------------------------------------------------------------
template <bool AF32, bool BF32, bool OUTF32>
__global__ __launch_bounds__(256) void gemm_kk(
    const void* __restrict__ Ap, const void* __restrict__ Bp,
    void* __restrict__ Cp, int M, int N, int K, int ldc, float scale) {
  // pad to 88 elems (176B row stride): 16B-aligned rows, 2-way (free) bank
  // pattern on ds_read_b128 per m136.
  __shared__ __align__(16) short At[128][88];
  __shared__ __align__(16) short Bt[128][88];
  const int tid = threadIdx.x;
  const int l = tid & 63;
  const int w = tid >> 6;
  const int wm = (w >> 1) * 64, wn = (w & 1) * 64;
  const int m0 = blockIdx.y * 128, n0 = blockIdx.x * 128;
  const int srow = tid >> 3, scol = (tid & 7) * 8;

  f32x4 acc[4][4];
#pragma unroll
  for (int i = 0; i < 4; ++i)
#pragma unroll
    for (int j = 0; j < 4; ++j) acc[i][j] = (f32x4){0.f, 0.f, 0.f, 0.f};

  for (int k0 = 0; k0 < K; k0 += 64) {
    __syncthreads();
#pragma unroll
    for (int c = 0; c < 4; ++c) {
      const int r = srow + c * 32;
      if (AF32) {
        const float* s = (const float*)Ap + (size_t)(m0 + r) * K + k0 + scol;
        const float4 f0 = *(const float4*)s;
        const float4 f1 = *(const float4*)(s + 4);
        bf16x8 v;
        v[0] = f2bf(f0.x); v[1] = f2bf(f0.y); v[2] = f2bf(f0.z); v[3] = f2bf(f0.w);
        v[4] = f2bf(f1.x); v[5] = f2bf(f1.y); v[6] = f2bf(f1.z); v[7] = f2bf(f1.w);
        *(bf16x8*)&At[r][scol] = v;
      } else {
        const short* s = (const short*)Ap + (size_t)(m0 + r) * K + k0 + scol;
        *(bf16x8*)&At[r][scol] = *(const bf16x8*)s;
      }
      if (BF32) {
        const float* s = (const float*)Bp + (size_t)(n0 + r) * K + k0 + scol;
        const float4 f0 = *(const float4*)s;
        const float4 f1 = *(const float4*)(s + 4);
        bf16x8 v;
        v[0] = f2bf(f0.x); v[1] = f2bf(f0.y); v[2] = f2bf(f0.z); v[3] = f2bf(f0.w);
        v[4] = f2bf(f1.x); v[5] = f2bf(f1.y); v[6] = f2bf(f1.z); v[7] = f2bf(f1.w);
        *(bf16x8*)&Bt[r][scol] = v;
      } else {
        const short* s = (const short*)Bp + (size_t)(n0 + r) * K + k0 + scol;
        *(bf16x8*)&Bt[r][scol] = *(const bf16x8*)s;
      }
    }
    __syncthreads();
#pragma unroll
    for (int ks = 0; ks < 2; ++ks) {
      bf16x8 af[4], bfr[4];
#pragma unroll
      for (int mt = 0; mt < 4; ++mt)
        af[mt] = *(const bf16x8*)&At[wm + mt * 16 + (l & 15)][ks * 32 + (l >> 4) * 8];
#pragma unroll
      for (int nt = 0; nt < 4; ++nt)
        bfr[nt] = *(const bf16x8*)&Bt[wn + nt * 16 + (l & 15)][ks * 32 + (l >> 4) * 8];
#pragma unroll
      for (int mt = 0; mt < 4; ++mt)
#pragma unroll
        for (int nt = 0; nt < 4; ++nt)
          acc[mt][nt] = MFMA16(af[mt], bfr[nt], acc[mt][nt]);
    }
  }
  // epilogue: C/D layout col = lane&15, row = (lane>>4)*4 + reg (m89)
#pragma unroll
  for (int mt = 0; mt < 4; ++mt)
#pragma unroll
    for (int nt = 0; nt < 4; ++nt)
#pragma unroll
      for (int r = 0; r < 4; ++r) {
        const int row = m0 + wm + mt * 16 + (l >> 4) * 4 + r;
        const int col = n0 + wn + nt * 16 + (l & 15);
        const float v = acc[mt][nt][r] * scale;
        if (OUTF32)
          ((float*)Cp)[(size_t)row * ldc + col] = v;
        else
          ((short*)Cp)[(size_t)row * ldc + col] = f2bf(v);
      }
}

// ---------------------------------------------------------------------------
// Flash attention. qb,kb: [b*2048+l][h*64+d] bf16 (q pre-scaled by 1/8).
// vT: [h*64+d][b*2048+kv] bf16.  ob out: [b*2048+q][h*64+d] bf16.
// Block: 256 thr = 4 waves; wave handles 16 q rows; KVBLK=64.
// ---------------------------------------------------------------------------
__global__ __launch_bounds__(256) void attn_kernel(
    const short* __restrict__ qb, const short* __restrict__ kb,
    const short* __restrict__ vT, short* __restrict__ ob) {
  __shared__ __align__(16) short Kt[64][88];   // [kv][d]
  __shared__ __align__(16) short Vt[64][88];   // [d][kv]
  __shared__ __align__(16) short Pl[4][16][88];// per-wave P [q][kv]
  const int tid = threadIdx.x, w = tid >> 6, l = tid & 63;
  const int bh = blockIdx.y, b = bh >> 4, h = bh & 15;
  const int q0 = blockIdx.x * 64 + w * 16;
  const int rowst = tid >> 3, colst = (tid & 7) * 8;

  // Q fragments stay in registers for all kv tiles
  bf16x8 qf[2];
  {
    const short* qrow =
        qb + (size_t)(b * 2048 + q0 + (l & 15)) * 1024 + h * 64 + (l >> 4) * 8;
    qf[0] = *(const bf16x8*)qrow;
    qf[1] = *(const bf16x8*)(qrow + 32);
  }
  f32x4 o[4];
#pragma unroll
  for (int dt = 0; dt < 4; ++dt) o[dt] = (f32x4){0.f, 0.f, 0.f, 0.f};
  float mrow[4], lrow[4];
#pragma unroll
  for (int r = 0; r < 4; ++r) { mrow[r] = -1e30f; lrow[r] = 0.f; }

  for (int kv0 = 0; kv0 < 2048; kv0 += 64) {
    __syncthreads();
#pragma unroll
    for (int c = 0; c < 2; ++c) {
      const int r = rowst + c * 32;
      *(bf16x8*)&Kt[r][colst] = *(const bf16x8*)(
          kb + (size_t)(b * 2048 + kv0 + r) * 1024 + h * 64 + colst);
      *(bf16x8*)&Vt[r][colst] = *(const bf16x8*)(
          vT + (size_t)(h * 64 + r) * 8192 + b * 2048 + kv0 + colst);
    }
    __syncthreads();

    // S = Q K^T : 4 col-tiles x 2 k-steps
    f32x4 s[4];
#pragma unroll
    for (int jt = 0; jt < 4; ++jt) {
      const bf16x8 kf0 = *(const bf16x8*)&Kt[jt * 16 + (l & 15)][(l >> 4) * 8];
      const bf16x8 kf1 = *(const bf16x8*)&Kt[jt * 16 + (l & 15)][32 + (l >> 4) * 8];
      f32x4 t = (f32x4){0.f, 0.f, 0.f, 0.f};
      t = MFMA16(qf[0], kf0, t);
      t = MFMA16(qf[1], kf1, t);
      s[jt] = t;
    }

    // online softmax, row i = (l>>4)*4 + r lives in 16 consecutive lanes
#pragma unroll
    for (int r = 0; r < 4; ++r) {
      float mx = fmaxf(fmaxf(s[0][r], s[1][r]), fmaxf(s[2][r], s[3][r]));
      mx = fmaxf(mx, __shfl_xor(mx, 1));
      mx = fmaxf(mx, __shfl_xor(mx, 2));
      mx = fmaxf(mx, __shfl_xor(mx, 4));
      mx = fmaxf(mx, __shfl_xor(mx, 8));
      const float mnew = fmaxf(mrow[r], mx);
      const float fac = __expf(mrow[r] - mnew);
      mrow[r] = mnew;
      float sum = 0.f;
#pragma unroll
      for (int jt = 0; jt < 4; ++jt) {
        const float p = __expf(s[jt][r] - mnew);
        s[jt][r] = p;
        sum += p;
      }
      sum += __shfl_xor(sum, 1);
      sum += __shfl_xor(sum, 2);
      sum += __shfl_xor(sum, 4);
      sum += __shfl_xor(sum, 8);
      lrow[r] = lrow[r] * fac + sum;
#pragma unroll
      for (int dt = 0; dt < 4; ++dt) o[dt][r] *= fac;
    }

    // P (C-layout) -> bf16 -> per-wave LDS -> A-fragment layout
#pragma unroll
    for (int jt = 0; jt < 4; ++jt)
#pragma unroll
      for (int r = 0; r < 4; ++r)
        Pl[w][(l >> 4) * 4 + r][jt * 16 + (l & 15)] = f2bf(s[jt][r]);
    __asm__ volatile("s_waitcnt lgkmcnt(0)" ::: "memory");
    __builtin_amdgcn_sched_barrier(0);
    const bf16x8 pa0 = *(const bf16x8*)&Pl[w][l & 15][(l >> 4) * 8];
    const bf16x8 pa1 = *(const bf16x8*)&Pl[w][l & 15][32 + (l >> 4) * 8];

    // O += P V
#pragma unroll
    for (int dt = 0; dt < 4; ++dt) {
      const bf16x8 vf0 = *(const bf16x8*)&Vt[dt * 16 + (l & 15)][(l >> 4) * 8];
      const bf16x8 vf1 = *(const bf16x8*)&Vt[dt * 16 + (l & 15)][32 + (l >> 4) * 8];
      o[dt] = MFMA16(pa0, vf0, o[dt]);
      o[dt] = MFMA16(pa1, vf1, o[dt]);
    }
  }

  float inv[4];
#pragma unroll
  for (int r = 0; r < 4; ++r) inv[r] = 1.0f / lrow[r];
#pragma unroll
  for (int dt = 0; dt < 4; ++dt)
#pragma unroll
    for (int r = 0; r < 4; ++r) {
      const size_t row = (size_t)(b * 2048 + q0 + (l >> 4) * 4 + r);
      ob[row * 1024 + h * 64 + dt * 16 + (l & 15)] = f2bf(o[dt][r] * inv[r]);
    }
}

// ---------------------------------------------------------------------------
extern "C" void kernel_launch(void* const* d_in, const int* in_sizes, int n_in,
                              void* d_out, int out_size, void* d_ws,
                              size_t ws_size, hipStream_t stream) {
  const size_t ML = (size_t)8192 * 1024;  // b*L x h*d elements
  short* qb = (short*)d_ws;
  short* kb = qb + ML;
  short* vT = kb + ML;
  short* ob = vT + ML;
  short* wT = ob + ML;  // 4 x 1024x1024 bf16
  short* WqT = wT;
  short* WkT = wT + (size_t)1024 * 1024;
  short* WvT = wT + (size_t)2 * 1024 * 1024;
  short* WoT = wT + (size_t)3 * 1024 * 1024;

  // weights -> bf16, transposed to [N][K]
  wtrans_kernel<<<dim3(32, 32, 4), 256, 0, stream>>>(
      (const float*)d_in[2], (const float*)d_in[3], (const float*)d_in[4],
      (const float*)d_in[5], wT);

  // q = inputs_q @ Wq / 8 ; k = inputs_kv @ Wk
  gemm_kk<true, false, false><<<dim3(8, 64), 256, 0, stream>>>(
      d_in[0], WqT, qb, 8192, 1024, 1024, 1024, 0.125f);
  gemm_kk<true, false, false><<<dim3(8, 64), 256, 0, stream>>>(
      d_in[1], WkT, kb, 8192, 1024, 1024, 1024, 1.0f);
  // vT = (inputs_kv @ Wv)^T computed directly: A=WvT[1024][1024], B=inputs_kv
  gemm_kk<false, true, false><<<dim3(64, 8), 256, 0, stream>>>(
      WvT, d_in[1], vT, 1024, 8192, 1024, 8192, 1.0f);

  attn_kernel<<<dim3(32, 64), 256, 0, stream>>>(qb, kb, vT, ob);

  // out = ob @ Wo  (f32 out)
  gemm_kk<false, false, true><<<dim3(8, 64), 256, 0, stream>>>(
      ob, WoT, d_out, 8192, 1024, 1024, 1024, 1.0f);
}

// Round 2
// 295.634 us; speedup vs baseline: 1.2466x; 1.2466x over previous
//
#include <hip/hip_runtime.h>
#include <hip/hip_bf16.h>

// MultiHeadDotProductAttention: b=4, L=2048, E=1024, H=16, D=64
// Pipeline: wtrans (f32->bf16, W^T) -> GEMM q,k,vT -> flash attn (32x32
// swapped-QK, in-register softmax) -> GEMM out.

typedef __attribute__((ext_vector_type(8))) short bf16x8;
typedef __attribute__((ext_vector_type(4))) float f32x4;
typedef __attribute__((ext_vector_type(16))) float f32x16;

#define MFMA16(a, b, c) __builtin_amdgcn_mfma_f32_16x16x32_bf16((a), (b), (c), 0, 0, 0)
#define MFMA32(a, b, c) __builtin_amdgcn_mfma_f32_32x32x16_bf16((a), (b), (c), 0, 0, 0)

__device__ __forceinline__ short f2bf(float f) {
  union { float f; unsigned u; } v; v.f = f;
  unsigned r = v.u + 0x7fffu + ((v.u >> 16) & 1u);  // RNE
  return (short)(r >> 16);
}

__device__ __forceinline__ unsigned cvtpk(float lo, float hi) {
  unsigned r;
  asm("v_cvt_pk_bf16_f32 %0, %1, %2" : "=v"(r) : "v"(lo), "v"(hi));
  return r;
}

__device__ __forceinline__ void plswap(unsigned& a, unsigned& b) {
  // swaps a's high 32 lanes with b's low 32 lanes
  asm volatile("v_permlane32_swap_b32 %0, %1" : "+v"(a), "+v"(b));
}

__device__ __forceinline__ void gld16(const short* g, short* l) {
  __builtin_amdgcn_global_load_lds(
      (const __attribute__((address_space(1))) unsigned int*)g,
      (__attribute__((address_space(3))) unsigned int*)l, 16, 0, 0);
}

// ---------------------------------------------------------------------------
// Weight transpose + convert: W[k][n] f32 (1024x1024) -> WT[n][k] bf16.
// ---------------------------------------------------------------------------
__global__ __launch_bounds__(256) void wtrans_kernel(
    const float* __restrict__ w0, const float* __restrict__ w1,
    const float* __restrict__ w2, const float* __restrict__ w3,
    short* __restrict__ out) {
  __shared__ float t[32][33];
  const int z = blockIdx.z;
  const float* src = (z == 0) ? w0 : (z == 1) ? w1 : (z == 2) ? w2 : w3;
  short* dst = out + (size_t)z * (1024 * 1024);
  const int x = threadIdx.x & 31, y = threadIdx.x >> 5;
  const int n0 = blockIdx.x * 32, k0 = blockIdx.y * 32;
#pragma unroll
  for (int yy = y; yy < 32; yy += 8)
    t[yy][x] = src[(size_t)(k0 + yy) * 1024 + n0 + x];
  __syncthreads();
#pragma unroll
  for (int yy = y; yy < 32; yy += 8)
    dst[(size_t)(n0 + yy) * 1024 + k0 + x] = f2bf(t[x][yy]);
}

// ---------------------------------------------------------------------------
// GEMM: C[M][N] = A[M][K] * B[N][K]^T (both k-major). 128x128 tile, BK=64.
// ---------------------------------------------------------------------------
template <bool AF32, bool BF32, bool OUTF32>
__global__ __launch_bounds__(256) void gemm_kk(
    const void* __restrict__ Ap, const void* __restrict__ Bp,
    void* __restrict__ Cp, int M, int N, int K, int ldc, float scale) {
  __shared__ __align__(16) short At[128][88];
  __shared__ __align__(16) short Bt[128][88];
  const int tid = threadIdx.x;
  const int l = tid & 63;
  const int w = tid >> 6;
  const int wm = (w >> 1) * 64, wn = (w & 1) * 64;
  const int m0 = blockIdx.y * 128, n0 = blockIdx.x * 128;
  const int srow = tid >> 3, scol = (tid & 7) * 8;

  f32x4 acc[4][4];
#pragma unroll
  for (int i = 0; i < 4; ++i)
#pragma unroll
    for (int j = 0; j < 4; ++j) acc[i][j] = (f32x4){0.f, 0.f, 0.f, 0.f};

  for (int k0 = 0; k0 < K; k0 += 64) {
    __syncthreads();
#pragma unroll
    for (int c = 0; c < 4; ++c) {
      const int r = srow + c * 32;
      if (AF32) {
        const float* s = (const float*)Ap + (size_t)(m0 + r) * K + k0 + scol;
        const float4 f0 = *(const float4*)s;
        const float4 f1 = *(const float4*)(s + 4);
        bf16x8 v;
        v[0] = f2bf(f0.x); v[1] = f2bf(f0.y); v[2] = f2bf(f0.z); v[3] = f2bf(f0.w);
        v[4] = f2bf(f1.x); v[5] = f2bf(f1.y); v[6] = f2bf(f1.z); v[7] = f2bf(f1.w);
        *(bf16x8*)&At[r][scol] = v;
      } else {
        const short* s = (const short*)Ap + (size_t)(m0 + r) * K + k0 + scol;
        *(bf16x8*)&At[r][scol] = *(const bf16x8*)s;
      }
      if (BF32) {
        const float* s = (const float*)Bp + (size_t)(n0 + r) * K + k0 + scol;
        const float4 f0 = *(const float4*)s;
        const float4 f1 = *(const float4*)(s + 4);
        bf16x8 v;
        v[0] = f2bf(f0.x); v[1] = f2bf(f0.y); v[2] = f2bf(f0.z); v[3] = f2bf(f0.w);
        v[4] = f2bf(f1.x); v[5] = f2bf(f1.y); v[6] = f2bf(f1.z); v[7] = f2bf(f1.w);
        *(bf16x8*)&Bt[r][scol] = v;
      } else {
        const short* s = (const short*)Bp + (size_t)(n0 + r) * K + k0 + scol;
        *(bf16x8*)&Bt[r][scol] = *(const bf16x8*)s;
      }
    }
    __syncthreads();
#pragma unroll
    for (int ks = 0; ks < 2; ++ks) {
      bf16x8 af[4], bfr[4];
#pragma unroll
      for (int mt = 0; mt < 4; ++mt)
        af[mt] = *(const bf16x8*)&At[wm + mt * 16 + (l & 15)][ks * 32 + (l >> 4) * 8];
#pragma unroll
      for (int nt = 0; nt < 4; ++nt)
        bfr[nt] = *(const bf16x8*)&Bt[wn + nt * 16 + (l & 15)][ks * 32 + (l >> 4) * 8];
#pragma unroll
      for (int mt = 0; mt < 4; ++mt)
#pragma unroll
        for (int nt = 0; nt < 4; ++nt)
          acc[mt][nt] = MFMA16(af[mt], bfr[nt], acc[mt][nt]);
    }
  }
#pragma unroll
  for (int mt = 0; mt < 4; ++mt)
#pragma unroll
    for (int nt = 0; nt < 4; ++nt)
#pragma unroll
      for (int r = 0; r < 4; ++r) {
        const int row = m0 + wm + mt * 16 + (l >> 4) * 4 + r;
        const int col = n0 + wn + nt * 16 + (l & 15);
        const float v = acc[mt][nt][r] * scale;
        if (OUTF32)
          ((float*)Cp)[(size_t)row * ldc + col] = v;
        else
          ((short*)Cp)[(size_t)row * ldc + col] = f2bf(v);
      }
}

// ---------------------------------------------------------------------------
// Flash attention, 32x32 swapped-QK structure.
// qb,kb: [b*2048+l][h*64+d] bf16 (q pre-scaled by log2e/8).
// vT: [h*64+d][b*2048+kv] bf16.  ob: [b*2048+q][h*64+d] bf16.
// Block = 256 thr (4 waves); wave owns 32 q rows; KVBLK=64.
// LDS K/V tiles [64][64] with 16B-block XOR swizzle (blk ^= row&7), written
// linearly by global_load_lds from a pre-swizzled global source (rule #21).
// S^T = mfma(K, Q^T): lane holds q=lane&31, kv=(r&3)+8*(r>>2)+4*(lane>>5).
// ---------------------------------------------------------------------------
__global__ __launch_bounds__(256) void attn32_kernel(
    const short* __restrict__ qb, const short* __restrict__ kb,
    const short* __restrict__ vT, short* __restrict__ ob) {
  __shared__ __align__(16) short Ksh[2][64][64];
  __shared__ __align__(16) short Vsh[2][64][64];
  const int tid = threadIdx.x, w = tid >> 6, l = tid & 63;
  const int hi = l >> 5, ln = l & 31;
  const int bh = blockIdx.y, b = bh >> 4, h = bh & 15;
  const size_t bL = (size_t)b * 2048;
  const int hd = h * 64;
  const int q0 = blockIdx.x * 128 + w * 32;

  // staging geometry: thread writes 16B at LDS row (w*8 + l>>3), blk (l&7);
  // content must be global block (blk ^ row&7)
  const int sr0 = w * 8 + (l >> 3);
  const int sc0 = ((l & 7) ^ (sr0 & 7)) << 3;

#define STAGE(BUF, KV0)                                                      \
  do {                                                                       \
    gld16(kb + (bL + (KV0) + sr0) * 1024 + hd + sc0, &Ksh[BUF][w * 8][0]);   \
    gld16(kb + (bL + (KV0) + sr0 + 32) * 1024 + hd + sc0,                    \
          &Ksh[BUF][32 + w * 8][0]);                                         \
    gld16(vT + (size_t)(hd + sr0) * 8192 + bL + (KV0) + sc0,                 \
          &Vsh[BUF][w * 8][0]);                                              \
    gld16(vT + (size_t)(hd + sr0 + 32) * 8192 + bL + (KV0) + sc0,            \
          &Vsh[BUF][32 + w * 8][0]);                                         \
  } while (0)

  // Q fragments (B-operand): qf[c][j] = Q[q=ln][d = c*16 + hi*8 + j]
  bf16x8 qf[4];
  {
    const short* qrow = qb + (bL + q0 + ln) * 1024 + hd + hi * 8;
#pragma unroll
    for (int c = 0; c < 4; ++c) qf[c] = *(const bf16x8*)(qrow + c * 16);
  }

  f32x16 o0, o1;
#pragma unroll
  for (int i = 0; i < 16; ++i) { o0[i] = 0.f; o1[i] = 0.f; }
  float m = -1e30f, lsum = 0.f;

  // swizzled LDS read column for fragment chunk c (row&7 == ln&7 both halves)
  const int swz = ln & 7;

  STAGE(0, 0);
  int cur = 0;
  for (int t = 0; t < 32; ++t) {
    __syncthreads();  // drains vmcnt: staging of `cur` complete; buffer safe
    if (t < 31) STAGE(cur ^ 1, (t + 1) * 64);

    // ---- S^T = K · Q^T over d chunks
    f32x16 s0, s1;
#pragma unroll
    for (int i = 0; i < 16; ++i) { s0[i] = 0.f; s1[i] = 0.f; }
#pragma unroll
    for (int c = 0; c < 4; ++c) {
      const int bcol = ((((c << 1) | hi)) ^ swz) << 3;
      const bf16x8 kf0 = *(const bf16x8*)&Ksh[cur][ln][bcol];
      const bf16x8 kf1 = *(const bf16x8*)&Ksh[cur][32 + ln][bcol];
      s0 = MFMA32(kf0, qf[c], s0);
      s1 = MFMA32(kf1, qf[c], s1);
    }

    // ---- online softmax (exp2 domain), lane-local row q = ln
    float pmax = s0[0];
#pragma unroll
    for (int i = 1; i < 16; ++i) pmax = fmaxf(pmax, s0[i]);
#pragma unroll
    for (int i = 0; i < 16; ++i) pmax = fmaxf(pmax, s1[i]);
    pmax = fmaxf(pmax, __shfl_xor(pmax, 32));
    const float mnew = fmaxf(m, pmax);
    const float fac = exp2f(m - mnew);
    m = mnew;
    float p0[16], p1[16];
    float sum = 0.f;
#pragma unroll
    for (int i = 0; i < 16; ++i) { p0[i] = exp2f(s0[i] - m); sum += p0[i]; }
#pragma unroll
    for (int i = 0; i < 16; ++i) { p1[i] = exp2f(s1[i] - m); sum += p1[i]; }
    sum += __shfl_xor(sum, 32);
    lsum = lsum * fac + sum;
#pragma unroll
    for (int i = 0; i < 16; ++i) { o0[i] *= fac; o1[i] *= fac; }

    // ---- O^T += V^T · P^T  (P packed in-register via cvt_pk + permlane)
#define PVCHUNK(PARR, BASE, C)                                               \
  do {                                                                       \
    unsigned A0 = cvtpk(PARR[(BASE) + 0], PARR[(BASE) + 1]);                 \
    unsigned A1 = cvtpk(PARR[(BASE) + 2], PARR[(BASE) + 3]);                 \
    unsigned B0 = cvtpk(PARR[(BASE) + 4], PARR[(BASE) + 5]);                 \
    unsigned B1 = cvtpk(PARR[(BASE) + 6], PARR[(BASE) + 7]);                 \
    plswap(A0, B0);                                                          \
    plswap(A1, B1);                                                          \
    union { unsigned u[4]; bf16x8 v; } pf;                                   \
    pf.u[0] = A0; pf.u[1] = A1; pf.u[2] = B0; pf.u[3] = B1;                  \
    const int bcol = ((((C) << 1) | hi) ^ swz) << 3;                         \
    const bf16x8 vf0 = *(const bf16x8*)&Vsh[cur][ln][bcol];                  \
    const bf16x8 vf1 = *(const bf16x8*)&Vsh[cur][32 + ln][bcol];             \
    o0 = MFMA32(vf0, pf.v, o0);                                              \
    o1 = MFMA32(vf1, pf.v, o1);                                              \
  } while (0)

    PVCHUNK(p0, 0, 0);
    PVCHUNK(p0, 8, 1);
    PVCHUNK(p1, 0, 2);
    PVCHUNK(p1, 8, 3);
#undef PVCHUNK

    cur ^= 1;
  }

  // ---- epilogue: O^T lane holds q=ln; d = (r&3)+8*(r>>2)+4*hi (+32 for o1)
  const float inv = 1.0f / lsum;
  short* orow = ob + (bL + q0 + ln) * 1024 + hd + hi * 4;
#pragma unroll
  for (int g = 0; g < 4; ++g) {
    const unsigned a0 = cvtpk(o0[4 * g + 0] * inv, o0[4 * g + 1] * inv);
    const unsigned a1 = cvtpk(o0[4 * g + 2] * inv, o0[4 * g + 3] * inv);
    *(uint2*)(orow + 8 * g) = make_uint2(a0, a1);
    const unsigned b0 = cvtpk(o1[4 * g + 0] * inv, o1[4 * g + 1] * inv);
    const unsigned b1 = cvtpk(o1[4 * g + 2] * inv, o1[4 * g + 3] * inv);
    *(uint2*)(orow + 32 + 8 * g) = make_uint2(b0, b1);
  }
#undef STAGE
}

// ---------------------------------------------------------------------------
extern "C" void kernel_launch(void* const* d_in, const int* in_sizes, int n_in,
                              void* d_out, int out_size, void* d_ws,
                              size_t ws_size, hipStream_t stream) {
  const size_t ML = (size_t)8192 * 1024;
  short* qb = (short*)d_ws;
  short* kb = qb + ML;
  short* vT = kb + ML;
  short* ob = vT + ML;
  short* wT = ob + ML;
  short* WqT = wT;
  short* WkT = wT + (size_t)1024 * 1024;
  short* WvT = wT + (size_t)2 * 1024 * 1024;
  short* WoT = wT + (size_t)3 * 1024 * 1024;

  wtrans_kernel<<<dim3(32, 32, 4), 256, 0, stream>>>(
      (const float*)d_in[2], (const float*)d_in[3], (const float*)d_in[4],
      (const float*)d_in[5], wT);

  // q = inputs_q @ Wq * (log2e / 8)  -> softmax runs in exp2 domain
  gemm_kk<true, false, false><<<dim3(8, 64), 256, 0, stream>>>(
      d_in[0], WqT, qb, 8192, 1024, 1024, 1024, 0.125f * 1.44269504f);
  gemm_kk<true, false, false><<<dim3(8, 64), 256, 0, stream>>>(
      d_in[1], WkT, kb, 8192, 1024, 1024, 1024, 1.0f);
  gemm_kk<false, true, false><<<dim3(64, 8), 256, 0, stream>>>(
      WvT, d_in[1], vT, 1024, 8192, 1024, 8192, 1.0f);

  attn32_kernel<<<dim3(16, 64), 256, 0, stream>>>(qb, kb, vT, ob);

  gemm_kk<false, false, true><<<dim3(8, 64), 256, 0, stream>>>(
      ob, WoT, d_out, 8192, 1024, 1024, 1024, 1.0f);
}

// Round 6
// 274.680 us; speedup vs baseline: 1.3418x; 1.0763x over previous
//
#include <hip/hip_runtime.h>
#include <hip/hip_bf16.h>

// MultiHeadDotProductAttention: b=4, L=2048, E=1024, H=16, D=64
// BISECTION ROUND: new bf16 GEMM path (gemm_bb + casts + aliasing) combined
// with the R1-PROVEN attn32 kernel (4-wave, full-rescale, shfl_xor reduces).
// Only addition to attn32: s_setprio hints (correctness-neutral).

typedef __attribute__((ext_vector_type(8))) short bf16x8;
typedef __attribute__((ext_vector_type(4))) float f32x4;
typedef __attribute__((ext_vector_type(16))) float f32x16;

#define MFMA16(a, b, c) __builtin_amdgcn_mfma_f32_16x16x32_bf16((a), (b), (c), 0, 0, 0)
#define MFMA32(a, b, c) __builtin_amdgcn_mfma_f32_32x32x16_bf16((a), (b), (c), 0, 0, 0)

__device__ __forceinline__ short f2bf(float f) {
  union { float f; unsigned u; } v; v.f = f;
  unsigned r = v.u + 0x7fffu + ((v.u >> 16) & 1u);  // RNE
  return (short)(r >> 16);
}

__device__ __forceinline__ unsigned cvtpk(float lo, float hi) {
  unsigned r;
  asm("v_cvt_pk_bf16_f32 %0, %1, %2" : "=v"(r) : "v"(lo), "v"(hi));
  return r;
}

__device__ __forceinline__ void plswap(unsigned& a, unsigned& b) {
  asm volatile("v_permlane32_swap_b32 %0, %1" : "+v"(a), "+v"(b));
}

__device__ __forceinline__ void gld16(const short* g, short* l) {
  __builtin_amdgcn_global_load_lds(
      (const __attribute__((address_space(1))) unsigned int*)g,
      (__attribute__((address_space(3))) unsigned int*)l, 16, 0, 0);
}

// ---------------------------------------------------------------------------
// f32 -> bf16 cast (row-major preserved), 8 elems/thread/iter, RNE.
// ---------------------------------------------------------------------------
__global__ __launch_bounds__(256) void cast_kernel(
    const float* __restrict__ in, short* __restrict__ out, int n8) {
  int i = blockIdx.x * 256 + threadIdx.x;
  const int stride = gridDim.x * 256;
  for (; i < n8; i += stride) {
    const float4 f0 = ((const float4*)in)[2 * i];
    const float4 f1 = ((const float4*)in)[2 * i + 1];
    bf16x8 v;
    v[0] = f2bf(f0.x); v[1] = f2bf(f0.y); v[2] = f2bf(f0.z); v[3] = f2bf(f0.w);
    v[4] = f2bf(f1.x); v[5] = f2bf(f1.y); v[6] = f2bf(f1.z); v[7] = f2bf(f1.w);
    ((bf16x8*)out)[i] = v;
  }
}

// ---------------------------------------------------------------------------
// Weight transpose + convert: W[k][n] f32 (1024x1024) -> WT[n][k] bf16 (RNE).
// ---------------------------------------------------------------------------
__global__ __launch_bounds__(256) void wtrans_kernel(
    const float* __restrict__ w0, const float* __restrict__ w1,
    const float* __restrict__ w2, const float* __restrict__ w3,
    short* __restrict__ out) {
  __shared__ float t[32][33];
  const int z = blockIdx.z;
  const float* src = (z == 0) ? w0 : (z == 1) ? w1 : (z == 2) ? w2 : w3;
  short* dst = out + (size_t)z * (1024 * 1024);
  const int x = threadIdx.x & 31, y = threadIdx.x >> 5;
  const int n0 = blockIdx.x * 32, k0 = blockIdx.y * 32;
#pragma unroll
  for (int yy = y; yy < 32; yy += 8)
    t[yy][x] = src[(size_t)(k0 + yy) * 1024 + n0 + x];
  __syncthreads();
#pragma unroll
  for (int yy = y; yy < 32; yy += 8)
    dst[(size_t)(n0 + yy) * 1024 + k0 + x] = f2bf(t[x][yy]);
}

// ---------------------------------------------------------------------------
// GEMM (m97 structure): C[M][N] = A[M][K] * B[N][K]^T, both bf16 k-major.
// 128x128 tile, BK=64, 4 waves 2x2 of 64x64, global_load_lds width-16
// staging into linear LDS, 2 barriers per K-step.
// ---------------------------------------------------------------------------
template <bool OUTF32>
__global__ __launch_bounds__(256) void gemm_bb(
    const short* __restrict__ A, const short* __restrict__ B,
    void* __restrict__ Cp, int M, int N, int K, int ldc, float scale) {
  __shared__ __align__(16) short At[128][64];
  __shared__ __align__(16) short Bt[128][64];
  const int tid = threadIdx.x, l = tid & 63, w = tid >> 6;
  const int wm = (w >> 1) * 64, wn = (w & 1) * 64;
  const int m0 = blockIdx.y * 128, n0 = blockIdx.x * 128;
  const short* Abase = A + (size_t)(m0 + w * 8 + (l >> 3)) * K + (l & 7) * 8;
  const short* Bbase = B + (size_t)(n0 + w * 8 + (l >> 3)) * K + (l & 7) * 8;

  f32x4 acc[4][4];
#pragma unroll
  for (int i = 0; i < 4; ++i)
#pragma unroll
    for (int j = 0; j < 4; ++j) acc[i][j] = (f32x4){0.f, 0.f, 0.f, 0.f};

  for (int k0 = 0; k0 < K; k0 += 64) {
    __syncthreads();
#pragma unroll
    for (int i = 0; i < 4; ++i) {
      gld16(Abase + (size_t)i * 32 * K + k0, &At[i * 32 + w * 8][0]);
      gld16(Bbase + (size_t)i * 32 * K + k0, &Bt[i * 32 + w * 8][0]);
    }
    __syncthreads();  // compiler emits vmcnt(0) before s_barrier -> data ready
#pragma unroll
    for (int ks = 0; ks < 2; ++ks) {
      bf16x8 af[4], bfr[4];
#pragma unroll
      for (int mt = 0; mt < 4; ++mt)
        af[mt] = *(const bf16x8*)&At[wm + mt * 16 + (l & 15)][ks * 32 + (l >> 4) * 8];
#pragma unroll
      for (int nt = 0; nt < 4; ++nt)
        bfr[nt] = *(const bf16x8*)&Bt[wn + nt * 16 + (l & 15)][ks * 32 + (l >> 4) * 8];
#pragma unroll
      for (int mt = 0; mt < 4; ++mt)
#pragma unroll
        for (int nt = 0; nt < 4; ++nt)
          acc[mt][nt] = MFMA16(af[mt], bfr[nt], acc[mt][nt]);
    }
  }
  // C/D layout: col = lane&15, row = (lane>>4)*4 + reg (m89)
#pragma unroll
  for (int mt = 0; mt < 4; ++mt)
#pragma unroll
    for (int nt = 0; nt < 4; ++nt)
#pragma unroll
      for (int r = 0; r < 4; ++r) {
        const int row = m0 + wm + mt * 16 + (l >> 4) * 4 + r;
        const int col = n0 + wn + nt * 16 + (l & 15);
        const float v = acc[mt][nt][r] * scale;
        if (OUTF32)
          ((float*)Cp)[(size_t)row * ldc + col] = v;
        else
          ((short*)Cp)[(size_t)row * ldc + col] = f2bf(v);
      }
}

// ---------------------------------------------------------------------------
// Flash attention — R1-PROVEN VERSION (verbatim except s_setprio hints).
// 4 waves x 32 q-rows, swapped-QK, full-rescale online softmax, shfl_xor
// cross-half reduces, cvt_pk+permlane P packing.
// ---------------------------------------------------------------------------
__global__ __launch_bounds__(256) void attn32_kernel(
    const short* __restrict__ qb, const short* __restrict__ kb,
    const short* __restrict__ vT, short* __restrict__ ob) {
  __shared__ __align__(16) short Ksh[2][64][64];
  __shared__ __align__(16) short Vsh[2][64][64];
  const int tid = threadIdx.x, w = tid >> 6, l = tid & 63;
  const int hi = l >> 5, ln = l & 31;
  const int bh = blockIdx.y, b = bh >> 4, h = bh & 15;
  const size_t bL = (size_t)b * 2048;
  const int hd = h * 64;
  const int q0 = blockIdx.x * 128 + w * 32;

  const int sr0 = w * 8 + (l >> 3);
  const int sc0 = ((l & 7) ^ (sr0 & 7)) << 3;

#define STAGE(BUF, KV0)                                                      \
  do {                                                                       \
    gld16(kb + (bL + (KV0) + sr0) * 1024 + hd + sc0, &Ksh[BUF][w * 8][0]);   \
    gld16(kb + (bL + (KV0) + sr0 + 32) * 1024 + hd + sc0,                    \
          &Ksh[BUF][32 + w * 8][0]);                                         \
    gld16(vT + (size_t)(hd + sr0) * 8192 + bL + (KV0) + sc0,                 \
          &Vsh[BUF][w * 8][0]);                                              \
    gld16(vT + (size_t)(hd + sr0 + 32) * 8192 + bL + (KV0) + sc0,            \
          &Vsh[BUF][32 + w * 8][0]);                                         \
  } while (0)

  bf16x8 qf[4];
  {
    const short* qrow = qb + (bL + q0 + ln) * 1024 + hd + hi * 8;
#pragma unroll
    for (int c = 0; c < 4; ++c) qf[c] = *(const bf16x8*)(qrow + c * 16);
  }

  f32x16 o0, o1;
#pragma unroll
  for (int i = 0; i < 16; ++i) { o0[i] = 0.f; o1[i] = 0.f; }
  float m = -1e30f, lsum = 0.f;

  const int swz = ln & 7;

  STAGE(0, 0);
  int cur = 0;
  for (int t = 0; t < 32; ++t) {
    __syncthreads();
    if (t < 31) STAGE(cur ^ 1, (t + 1) * 64);

    // ---- S^T = K · Q^T over d chunks
    f32x16 s0, s1;
#pragma unroll
    for (int i = 0; i < 16; ++i) { s0[i] = 0.f; s1[i] = 0.f; }
    __builtin_amdgcn_s_setprio(1);
#pragma unroll
    for (int c = 0; c < 4; ++c) {
      const int bcol = ((((c << 1) | hi)) ^ swz) << 3;
      const bf16x8 kf0 = *(const bf16x8*)&Ksh[cur][ln][bcol];
      const bf16x8 kf1 = *(const bf16x8*)&Ksh[cur][32 + ln][bcol];
      s0 = MFMA32(kf0, qf[c], s0);
      s1 = MFMA32(kf1, qf[c], s1);
    }
    __builtin_amdgcn_s_setprio(0);

    // ---- online softmax (exp2 domain), lane-local row q = ln
    float pmax = s0[0];
#pragma unroll
    for (int i = 1; i < 16; ++i) pmax = fmaxf(pmax, s0[i]);
#pragma unroll
    for (int i = 0; i < 16; ++i) pmax = fmaxf(pmax, s1[i]);
    pmax = fmaxf(pmax, __shfl_xor(pmax, 32));
    const float mnew = fmaxf(m, pmax);
    const float fac = exp2f(m - mnew);
    m = mnew;
    float p0[16], p1[16];
    float sum = 0.f;
#pragma unroll
    for (int i = 0; i < 16; ++i) { p0[i] = exp2f(s0[i] - m); sum += p0[i]; }
#pragma unroll
    for (int i = 0; i < 16; ++i) { p1[i] = exp2f(s1[i] - m); sum += p1[i]; }
    sum += __shfl_xor(sum, 32);
    lsum = lsum * fac + sum;
#pragma unroll
    for (int i = 0; i < 16; ++i) { o0[i] *= fac; o1[i] *= fac; }

    // ---- O^T += V^T · P^T  (P packed in-register via cvt_pk + permlane)
    __builtin_amdgcn_s_setprio(1);
#define PVCHUNK(PARR, BASE, C)                                               \
  do {                                                                       \
    unsigned A0 = cvtpk(PARR[(BASE) + 0], PARR[(BASE) + 1]);                 \
    unsigned A1 = cvtpk(PARR[(BASE) + 2], PARR[(BASE) + 3]);                 \
    unsigned B0 = cvtpk(PARR[(BASE) + 4], PARR[(BASE) + 5]);                 \
    unsigned B1 = cvtpk(PARR[(BASE) + 6], PARR[(BASE) + 7]);                 \
    plswap(A0, B0);                                                          \
    plswap(A1, B1);                                                          \
    union { unsigned u[4]; bf16x8 v; } pf;                                   \
    pf.u[0] = A0; pf.u[1] = A1; pf.u[2] = B0; pf.u[3] = B1;                  \
    const int bcol = ((((C) << 1) | hi) ^ swz) << 3;                         \
    const bf16x8 vf0 = *(const bf16x8*)&Vsh[cur][ln][bcol];                  \
    const bf16x8 vf1 = *(const bf16x8*)&Vsh[cur][32 + ln][bcol];             \
    o0 = MFMA32(vf0, pf.v, o0);                                              \
    o1 = MFMA32(vf1, pf.v, o1);                                              \
  } while (0)

    PVCHUNK(p0, 0, 0);
    PVCHUNK(p0, 8, 1);
    PVCHUNK(p1, 0, 2);
    PVCHUNK(p1, 8, 3);
#undef PVCHUNK
    __builtin_amdgcn_s_setprio(0);

    cur ^= 1;
  }

  // ---- epilogue: lane holds q=ln; d = (r&3)+8*(r>>2)+4*hi (+32 for o1)
  const float inv = 1.0f / lsum;
  short* orow = ob + (bL + q0 + ln) * 1024 + hd + hi * 4;
#pragma unroll
  for (int g = 0; g < 4; ++g) {
    const unsigned a0 = cvtpk(o0[4 * g + 0] * inv, o0[4 * g + 1] * inv);
    const unsigned a1 = cvtpk(o0[4 * g + 2] * inv, o0[4 * g + 3] * inv);
    *(uint2*)(orow + 8 * g) = make_uint2(a0, a1);
    const unsigned b0 = cvtpk(o1[4 * g + 0] * inv, o1[4 * g + 1] * inv);
    const unsigned b1 = cvtpk(o1[4 * g + 2] * inv, o1[4 * g + 3] * inv);
    *(uint2*)(orow + 32 + 8 * g) = make_uint2(b0, b1);
  }
#undef STAGE
}

// ---------------------------------------------------------------------------
// Workspace layout (72 MiB): qb, kb, vT, ob: 4 x 16 MiB; wT: 8 MiB.
// Cast scratch aliased into dead regions:
//   qibf -> vT region (dead after gemm_q, before gemm_vT writes vT)
//   kvbf -> ob region (dead after gemm_vT, before attn writes ob)
// ---------------------------------------------------------------------------
extern "C" void kernel_launch(void* const* d_in, const int* in_sizes, int n_in,
                              void* d_out, int out_size, void* d_ws,
                              size_t ws_size, hipStream_t stream) {
  const size_t ML = (size_t)8192 * 1024;
  short* qb = (short*)d_ws;
  short* kb = qb + ML;
  short* vT = kb + ML;
  short* ob = vT + ML;
  short* wT = ob + ML;  // 4 x 1024x1024 bf16
  short* WqT = wT;
  short* WkT = wT + (size_t)1024 * 1024;
  short* WvT = wT + (size_t)2 * 1024 * 1024;
  short* WoT = wT + (size_t)3 * 1024 * 1024;
  short* qibf = vT;  // aliased cast scratch
  short* kvbf = ob;

  wtrans_kernel<<<dim3(32, 32, 4), 256, 0, stream>>>(
      (const float*)d_in[2], (const float*)d_in[3], (const float*)d_in[4],
      (const float*)d_in[5], wT);

  cast_kernel<<<2048, 256, 0, stream>>>((const float*)d_in[0], qibf,
                                        (int)(ML / 8));
  cast_kernel<<<2048, 256, 0, stream>>>((const float*)d_in[1], kvbf,
                                        (int)(ML / 8));

  // q = inputs_q @ Wq * (log2e / 8)  -> softmax runs in exp2 domain
  gemm_bb<false><<<dim3(8, 64), 256, 0, stream>>>(
      qibf, WqT, qb, 8192, 1024, 1024, 1024, 0.125f * 1.44269504f);
  gemm_bb<false><<<dim3(8, 64), 256, 0, stream>>>(
      kvbf, WkT, kb, 8192, 1024, 1024, 1024, 1.0f);
  // vT = (inputs_kv @ Wv)^T directly: A=WvT [1024][1024], B=kvbf [8192][1024]
  gemm_bb<false><<<dim3(64, 8), 256, 0, stream>>>(
      WvT, kvbf, vT, 1024, 8192, 1024, 8192, 1.0f);

  attn32_kernel<<<dim3(16, 64), 256, 0, stream>>>(qb, kb, vT, ob);

  // out = ob @ Wo (f32 out)
  gemm_bb<true><<<dim3(8, 64), 256, 0, stream>>>(
      ob, WoT, d_out, 8192, 1024, 1024, 1024, 1.0f);
}

// Round 7
// 259.377 us; speedup vs baseline: 1.4209x; 1.0590x over previous
//
#include <hip/hip_runtime.h>
#include <hip/hip_bf16.h>

// MultiHeadDotProductAttention: b=4, L=2048, E=1024, H=16, D=64
// BISECTION STEP 2: R6-proven kernel + 8-wave attn geometry ONLY.
// (defer-max and permlane cross-half reduces remain quarantined; softmax is
// full-rescale with __shfl_xor, exactly as the passing R6 kernel.)

typedef __attribute__((ext_vector_type(8))) short bf16x8;
typedef __attribute__((ext_vector_type(4))) float f32x4;
typedef __attribute__((ext_vector_type(16))) float f32x16;

#define MFMA16(a, b, c) __builtin_amdgcn_mfma_f32_16x16x32_bf16((a), (b), (c), 0, 0, 0)
#define MFMA32(a, b, c) __builtin_amdgcn_mfma_f32_32x32x16_bf16((a), (b), (c), 0, 0, 0)

__device__ __forceinline__ short f2bf(float f) {
  union { float f; unsigned u; } v; v.f = f;
  unsigned r = v.u + 0x7fffu + ((v.u >> 16) & 1u);  // RNE
  return (short)(r >> 16);
}

__device__ __forceinline__ unsigned cvtpk(float lo, float hi) {
  unsigned r;
  asm("v_cvt_pk_bf16_f32 %0, %1, %2" : "=v"(r) : "v"(lo), "v"(hi));
  return r;
}

__device__ __forceinline__ void plswap(unsigned& a, unsigned& b) {
  asm volatile("v_permlane32_swap_b32 %0, %1" : "+v"(a), "+v"(b));
}

__device__ __forceinline__ void gld16(const short* g, short* l) {
  __builtin_amdgcn_global_load_lds(
      (const __attribute__((address_space(1))) unsigned int*)g,
      (__attribute__((address_space(3))) unsigned int*)l, 16, 0, 0);
}

// ---------------------------------------------------------------------------
// f32 -> bf16 cast (row-major preserved), 8 elems/thread/iter, RNE.
// ---------------------------------------------------------------------------
__global__ __launch_bounds__(256) void cast_kernel(
    const float* __restrict__ in, short* __restrict__ out, int n8) {
  int i = blockIdx.x * 256 + threadIdx.x;
  const int stride = gridDim.x * 256;
  for (; i < n8; i += stride) {
    const float4 f0 = ((const float4*)in)[2 * i];
    const float4 f1 = ((const float4*)in)[2 * i + 1];
    bf16x8 v;
    v[0] = f2bf(f0.x); v[1] = f2bf(f0.y); v[2] = f2bf(f0.z); v[3] = f2bf(f0.w);
    v[4] = f2bf(f1.x); v[5] = f2bf(f1.y); v[6] = f2bf(f1.z); v[7] = f2bf(f1.w);
    ((bf16x8*)out)[i] = v;
  }
}

// ---------------------------------------------------------------------------
// Weight transpose + convert: W[k][n] f32 (1024x1024) -> WT[n][k] bf16 (RNE).
// ---------------------------------------------------------------------------
__global__ __launch_bounds__(256) void wtrans_kernel(
    const float* __restrict__ w0, const float* __restrict__ w1,
    const float* __restrict__ w2, const float* __restrict__ w3,
    short* __restrict__ out) {
  __shared__ float t[32][33];
  const int z = blockIdx.z;
  const float* src = (z == 0) ? w0 : (z == 1) ? w1 : (z == 2) ? w2 : w3;
  short* dst = out + (size_t)z * (1024 * 1024);
  const int x = threadIdx.x & 31, y = threadIdx.x >> 5;
  const int n0 = blockIdx.x * 32, k0 = blockIdx.y * 32;
#pragma unroll
  for (int yy = y; yy < 32; yy += 8)
    t[yy][x] = src[(size_t)(k0 + yy) * 1024 + n0 + x];
  __syncthreads();
#pragma unroll
  for (int yy = y; yy < 32; yy += 8)
    dst[(size_t)(n0 + yy) * 1024 + k0 + x] = f2bf(t[x][yy]);
}

// ---------------------------------------------------------------------------
// GEMM (m97 structure): C[M][N] = A[M][K] * B[N][K]^T, both bf16 k-major.
// 128x128 tile, BK=64, 4 waves 2x2 of 64x64, global_load_lds width-16
// staging into linear LDS, 2 barriers per K-step.  (R6-proven.)
// ---------------------------------------------------------------------------
template <bool OUTF32>
__global__ __launch_bounds__(256) void gemm_bb(
    const short* __restrict__ A, const short* __restrict__ B,
    void* __restrict__ Cp, int M, int N, int K, int ldc, float scale) {
  __shared__ __align__(16) short At[128][64];
  __shared__ __align__(16) short Bt[128][64];
  const int tid = threadIdx.x, l = tid & 63, w = tid >> 6;
  const int wm = (w >> 1) * 64, wn = (w & 1) * 64;
  const int m0 = blockIdx.y * 128, n0 = blockIdx.x * 128;
  const short* Abase = A + (size_t)(m0 + w * 8 + (l >> 3)) * K + (l & 7) * 8;
  const short* Bbase = B + (size_t)(n0 + w * 8 + (l >> 3)) * K + (l & 7) * 8;

  f32x4 acc[4][4];
#pragma unroll
  for (int i = 0; i < 4; ++i)
#pragma unroll
    for (int j = 0; j < 4; ++j) acc[i][j] = (f32x4){0.f, 0.f, 0.f, 0.f};

  for (int k0 = 0; k0 < K; k0 += 64) {
    __syncthreads();
#pragma unroll
    for (int i = 0; i < 4; ++i) {
      gld16(Abase + (size_t)i * 32 * K + k0, &At[i * 32 + w * 8][0]);
      gld16(Bbase + (size_t)i * 32 * K + k0, &Bt[i * 32 + w * 8][0]);
    }
    __syncthreads();  // compiler emits vmcnt(0) before s_barrier -> data ready
#pragma unroll
    for (int ks = 0; ks < 2; ++ks) {
      bf16x8 af[4], bfr[4];
#pragma unroll
      for (int mt = 0; mt < 4; ++mt)
        af[mt] = *(const bf16x8*)&At[wm + mt * 16 + (l & 15)][ks * 32 + (l >> 4) * 8];
#pragma unroll
      for (int nt = 0; nt < 4; ++nt)
        bfr[nt] = *(const bf16x8*)&Bt[wn + nt * 16 + (l & 15)][ks * 32 + (l >> 4) * 8];
#pragma unroll
      for (int mt = 0; mt < 4; ++mt)
#pragma unroll
        for (int nt = 0; nt < 4; ++nt)
          acc[mt][nt] = MFMA16(af[mt], bfr[nt], acc[mt][nt]);
    }
  }
  // C/D layout: col = lane&15, row = (lane>>4)*4 + reg (m89)
#pragma unroll
  for (int mt = 0; mt < 4; ++mt)
#pragma unroll
    for (int nt = 0; nt < 4; ++nt)
#pragma unroll
      for (int r = 0; r < 4; ++r) {
        const int row = m0 + wm + mt * 16 + (l >> 4) * 4 + r;
        const int col = n0 + wn + nt * 16 + (l & 15);
        const float v = acc[mt][nt][r] * scale;
        if (OUTF32)
          ((float*)Cp)[(size_t)row * ldc + col] = v;
        else
          ((short*)Cp)[(size_t)row * ldc + col] = f2bf(v);
      }
}

// ---------------------------------------------------------------------------
// Flash attention: R6-proven math (full-rescale softmax, shfl_xor cross-half
// reduces, cvt_pk+permlane P packing, setprio) with 8-WAVE geometry:
// block = 512 thr = 8 waves x 32 q-rows = 256 q per block; each wave stages
// 8 K-rows + 8 V-rows (one gld16 each) per 64-kv tile.
// ---------------------------------------------------------------------------
__global__ __launch_bounds__(512) void attn8w_kernel(
    const short* __restrict__ qb, const short* __restrict__ kb,
    const short* __restrict__ vT, short* __restrict__ ob) {
  __shared__ __align__(16) short Ksh[2][64][64];
  __shared__ __align__(16) short Vsh[2][64][64];
  const int tid = threadIdx.x, w = tid >> 6, l = tid & 63;
  const int hi = l >> 5, ln = l & 31;
  const int bh = blockIdx.y, b = bh >> 4, h = bh & 15;
  const size_t bL = (size_t)b * 2048;
  const int hd = h * 64;
  const int q0 = blockIdx.x * 256 + w * 32;

  // staging: wave w stages rows w*8..w*8+7 of K and of V (1 gld16 each)
  const int sr0 = w * 8 + (l >> 3);
  const int sc0 = ((l & 7) ^ (sr0 & 7)) << 3;  // pre-swizzled source col

#define STAGE(BUF, KV0)                                                    \
  do {                                                                     \
    gld16(kb + (bL + (KV0) + sr0) * 1024 + hd + sc0, &Ksh[BUF][w * 8][0]); \
    gld16(vT + (size_t)(hd + sr0) * 8192 + bL + (KV0) + sc0,               \
          &Vsh[BUF][w * 8][0]);                                            \
  } while (0)

  bf16x8 qf[4];
  {
    const short* qrow = qb + (bL + q0 + ln) * 1024 + hd + hi * 8;
#pragma unroll
    for (int c = 0; c < 4; ++c) qf[c] = *(const bf16x8*)(qrow + c * 16);
  }

  f32x16 o0, o1;
#pragma unroll
  for (int i = 0; i < 16; ++i) { o0[i] = 0.f; o1[i] = 0.f; }
  float m = -1e30f, lsum = 0.f;

  const int swz = ln & 7;

  STAGE(0, 0);
  int cur = 0;
  for (int t = 0; t < 32; ++t) {
    __syncthreads();
    if (t < 31) STAGE(cur ^ 1, (t + 1) * 64);

    // ---- S^T = K · Q^T over d chunks
    f32x16 s0, s1;
#pragma unroll
    for (int i = 0; i < 16; ++i) { s0[i] = 0.f; s1[i] = 0.f; }
    __builtin_amdgcn_s_setprio(1);
#pragma unroll
    for (int c = 0; c < 4; ++c) {
      const int bcol = ((((c << 1) | hi)) ^ swz) << 3;
      const bf16x8 kf0 = *(const bf16x8*)&Ksh[cur][ln][bcol];
      const bf16x8 kf1 = *(const bf16x8*)&Ksh[cur][32 + ln][bcol];
      s0 = MFMA32(kf0, qf[c], s0);
      s1 = MFMA32(kf1, qf[c], s1);
    }
    __builtin_amdgcn_s_setprio(0);

    // ---- online softmax (exp2 domain), lane-local row q = ln
    float pmax = s0[0];
#pragma unroll
    for (int i = 1; i < 16; ++i) pmax = fmaxf(pmax, s0[i]);
#pragma unroll
    for (int i = 0; i < 16; ++i) pmax = fmaxf(pmax, s1[i]);
    pmax = fmaxf(pmax, __shfl_xor(pmax, 32));
    const float mnew = fmaxf(m, pmax);
    const float fac = exp2f(m - mnew);
    m = mnew;
    float p0[16], p1[16];
    float sum = 0.f;
#pragma unroll
    for (int i = 0; i < 16; ++i) { p0[i] = exp2f(s0[i] - m); sum += p0[i]; }
#pragma unroll
    for (int i = 0; i < 16; ++i) { p1[i] = exp2f(s1[i] - m); sum += p1[i]; }
    sum += __shfl_xor(sum, 32);
    lsum = lsum * fac + sum;
#pragma unroll
    for (int i = 0; i < 16; ++i) { o0[i] *= fac; o1[i] *= fac; }

    // ---- O^T += V^T · P^T  (P packed in-register via cvt_pk + permlane)
    __builtin_amdgcn_s_setprio(1);
#define PVCHUNK(PARR, BASE, C)                                               \
  do {                                                                       \
    unsigned A0 = cvtpk(PARR[(BASE) + 0], PARR[(BASE) + 1]);                 \
    unsigned A1 = cvtpk(PARR[(BASE) + 2], PARR[(BASE) + 3]);                 \
    unsigned B0 = cvtpk(PARR[(BASE) + 4], PARR[(BASE) + 5]);                 \
    unsigned B1 = cvtpk(PARR[(BASE) + 6], PARR[(BASE) + 7]);                 \
    plswap(A0, B0);                                                          \
    plswap(A1, B1);                                                          \
    union { unsigned u[4]; bf16x8 v; } pf;                                   \
    pf.u[0] = A0; pf.u[1] = A1; pf.u[2] = B0; pf.u[3] = B1;                  \
    const int bcol = ((((C) << 1) | hi) ^ swz) << 3;                         \
    const bf16x8 vf0 = *(const bf16x8*)&Vsh[cur][ln][bcol];                  \
    const bf16x8 vf1 = *(const bf16x8*)&Vsh[cur][32 + ln][bcol];             \
    o0 = MFMA32(vf0, pf.v, o0);                                              \
    o1 = MFMA32(vf1, pf.v, o1);                                              \
  } while (0)

    PVCHUNK(p0, 0, 0);
    PVCHUNK(p0, 8, 1);
    PVCHUNK(p1, 0, 2);
    PVCHUNK(p1, 8, 3);
#undef PVCHUNK
    __builtin_amdgcn_s_setprio(0);

    cur ^= 1;
  }

  // ---- epilogue: lane holds q=ln; d = (r&3)+8*(r>>2)+4*hi (+32 for o1)
  const float inv = 1.0f / lsum;
  short* orow = ob + (bL + q0 + ln) * 1024 + hd + hi * 4;
#pragma unroll
  for (int g = 0; g < 4; ++g) {
    const unsigned a0 = cvtpk(o0[4 * g + 0] * inv, o0[4 * g + 1] * inv);
    const unsigned a1 = cvtpk(o0[4 * g + 2] * inv, o0[4 * g + 3] * inv);
    *(uint2*)(orow + 8 * g) = make_uint2(a0, a1);
    const unsigned b0 = cvtpk(o1[4 * g + 0] * inv, o1[4 * g + 1] * inv);
    const unsigned b1 = cvtpk(o1[4 * g + 2] * inv, o1[4 * g + 3] * inv);
    *(uint2*)(orow + 32 + 8 * g) = make_uint2(b0, b1);
  }
#undef STAGE
}

// ---------------------------------------------------------------------------
// Workspace layout (72 MiB): qb, kb, vT, ob: 4 x 16 MiB; wT: 8 MiB.
// Cast scratch aliased into dead regions:
//   qibf -> vT region (dead after gemm_q, before gemm_vT writes vT)
//   kvbf -> ob region (dead after gemm_vT, before attn writes ob)
// ---------------------------------------------------------------------------
extern "C" void kernel_launch(void* const* d_in, const int* in_sizes, int n_in,
                              void* d_out, int out_size, void* d_ws,
                              size_t ws_size, hipStream_t stream) {
  const size_t ML = (size_t)8192 * 1024;
  short* qb = (short*)d_ws;
  short* kb = qb + ML;
  short* vT = kb + ML;
  short* ob = vT + ML;
  short* wT = ob + ML;  // 4 x 1024x1024 bf16
  short* WqT = wT;
  short* WkT = wT + (size_t)1024 * 1024;
  short* WvT = wT + (size_t)2 * 1024 * 1024;
  short* WoT = wT + (size_t)3 * 1024 * 1024;
  short* qibf = vT;  // aliased cast scratch
  short* kvbf = ob;

  wtrans_kernel<<<dim3(32, 32, 4), 256, 0, stream>>>(
      (const float*)d_in[2], (const float*)d_in[3], (const float*)d_in[4],
      (const float*)d_in[5], wT);

  cast_kernel<<<2048, 256, 0, stream>>>((const float*)d_in[0], qibf,
                                        (int)(ML / 8));
  cast_kernel<<<2048, 256, 0, stream>>>((const float*)d_in[1], kvbf,
                                        (int)(ML / 8));

  // q = inputs_q @ Wq * (log2e / 8)  -> softmax runs in exp2 domain
  gemm_bb<false><<<dim3(8, 64), 256, 0, stream>>>(
      qibf, WqT, qb, 8192, 1024, 1024, 1024, 0.125f * 1.44269504f);
  gemm_bb<false><<<dim3(8, 64), 256, 0, stream>>>(
      kvbf, WkT, kb, 8192, 1024, 1024, 1024, 1.0f);
  // vT = (inputs_kv @ Wv)^T directly: A=WvT [1024][1024], B=kvbf [8192][1024]
  gemm_bb<false><<<dim3(64, 8), 256, 0, stream>>>(
      WvT, kvbf, vT, 1024, 8192, 1024, 8192, 1.0f);

  attn8w_kernel<<<dim3(8, 64), 512, 0, stream>>>(qb, kb, vT, ob);

  // out = ob @ Wo (f32 out)
  gemm_bb<true><<<dim3(8, 64), 256, 0, stream>>>(
      ob, WoT, d_out, 8192, 1024, 1024, 1024, 1.0f);
}